// Round 3
// baseline (1334.097 us; speedup 1.0000x reference)
//
#include <hip/hip_runtime.h>
#include <cfloat>

#define NN 50000
#define EE 1600000
#define NEG 0.2f
#define BSH 6
#define BSZ 64                        // nodes per bucket
#define NBK ((NN + BSZ - 1) / BSZ)    // 782
#define CAP 8192                      // bucket staging capacity (avg ~2048)

__device__ inline float leaky(float v) { return v >= 0.f ? v : NEG * v; }

// ---------------------------------------------------------------------------
// GEMM: h = feat@Wg + bg ; hp = feat@Wp + bp ; ssrc = h@a_src ; sdst = h@a_dst
__global__ __launch_bounds__(256) void k_gemm(
    const float* __restrict__ feat, const float* __restrict__ Wg,
    const float* __restrict__ bg, const float* __restrict__ as_,
    const float* __restrict__ ad_, const float* __restrict__ Wp,
    const float* __restrict__ bp,
    float* __restrict__ h, float* __restrict__ hp,
    float* __restrict__ ssrc, float* __restrict__ sdst)
{
    __shared__ float sWg[64 * 64];
    __shared__ float sWp[64 * 64];
    __shared__ float sb[4 * 64];
    int t = threadIdx.x;
    for (int i = t; i < 4096; i += 256) { sWg[i] = Wg[i]; sWp[i] = Wp[i]; }
    if (t < 64)       sb[t] = bg[t];
    else if (t < 128) sb[t] = bp[t - 64];
    else if (t < 192) sb[t] = as_[t - 128];
    else              sb[t] = ad_[t - 192];
    __syncthreads();

    int lane = t & 63;
    int w    = t >> 6;
    int nw   = (gridDim.x * blockDim.x) >> 6;
    for (int n = blockIdx.x * 4 + w; n < NN; n += nw) {
        float fv   = feat[n * 64 + lane];
        float accg = sb[lane];
        float accp = sb[64 + lane];
#pragma unroll
        for (int k = 0; k < 64; ++k) {
            float f = __shfl(fv, k, 64);
            accg = fmaf(f, sWg[k * 64 + lane], accg);
            accp = fmaf(f, sWp[k * 64 + lane], accp);
        }
        h [n * 64 + lane] = accg;
        hp[n * 64 + lane] = accp;
        float vs = accg * sb[128 + lane];
        float vd = accg * sb[192 + lane];
#pragma unroll
        for (int off = 32; off > 0; off >>= 1) {
            vs += __shfl_xor(vs, off, 64);
            vd += __shfl_xor(vd, off, 64);
        }
        if (lane == 0) { ssrc[n] = vs; sdst[n] = vd; }
    }
}

// ---------------------------------------------------------------------------
__global__ void k_zero(int* __restrict__ bcnt)
{
    int i = blockIdx.x * blockDim.x + threadIdx.x;
    if (i < 3 * NBK) bcnt[i] = 0;
}

// bucket histogram, LDS-privatized.
__global__ __launch_bounds__(256) void k_bhist(
    const int* __restrict__ lu, const int* __restrict__ ld,
    const int* __restrict__ pi, int* __restrict__ bcnt)
{
    __shared__ int lh[3 * NBK];
    for (int i = threadIdx.x; i < 3 * NBK; i += 256) lh[i] = 0;
    __syncthreads();
    int stride = gridDim.x * blockDim.x;
    for (int i = blockIdx.x * blockDim.x + threadIdx.x; i < 3 * EE; i += stride) {
        int slot;
        if (i < EE)          slot = 0 * NBK + (lu[EE + i] >> BSH);
        else if (i < 2 * EE) slot = 1 * NBK + (ld[i] >> BSH);       // ld[EE+(i-EE)]
        else                 slot = 2 * NBK + (pi[i - 2 * EE] >> BSH);
        atomicAdd(&lh[slot], 1);
    }
    __syncthreads();
    for (int i = threadIdx.x; i < 3 * NBK; i += 256)
        if (lh[i]) atomicAdd(&bcnt[i], lh[i]);
}

// scan bucket counts per list -> bases + cursors; also off[l][NN] = EE.
__global__ __launch_bounds__(256) void k_bscan(
    const int* __restrict__ bcnt, int* __restrict__ bbase,
    int* __restrict__ bcur, int* __restrict__ off)
{
    __shared__ int part[256];
    int t = threadIdx.x;
    for (int l = 0; l < 3; ++l) {
        const int* cb = bcnt + l * NBK;
        int* bb = bbase + l * (NBK + 1);
        int* bc = bcur + l * NBK;
        const int CH = (NBK + 255) / 256;
        int lo = t * CH, hi = min(lo + CH, NBK);
        int s = 0;
        for (int i = lo; i < hi; ++i) s += cb[i];
        part[t] = s;
        __syncthreads();
        for (int d = 1; d < 256; d <<= 1) {
            int v = 0;
            if (t >= d) v = part[t - d];
            __syncthreads();
            if (t >= d) part[t] += v;
            __syncthreads();
        }
        int run = (t == 0) ? 0 : part[t - 1];
        for (int i = lo; i < hi; ++i) { bb[i] = run; bc[i] = run; run += cb[i]; }
        if (t == 0) { bb[NBK] = EE; off[l * (NN + 1) + NN] = EE; }
        __syncthreads();
    }
}

// scatter edges into bucket regions (packed payload).
__global__ void k_bfill(
    const int* __restrict__ lu, const int* __restrict__ ld,
    const int* __restrict__ pi, const float* __restrict__ pv,
    int* __restrict__ bcur,
    unsigned* __restrict__ bglu, unsigned* __restrict__ bgld,
    unsigned* __restrict__ bgpc, float* __restrict__ bgpv)
{
    int i = blockIdx.x * blockDim.x + threadIdx.x;
    if (i >= 3 * EE) return;
    if (i < EE) {
        int s = lu[i], d = lu[EE + i];
        int pos = atomicAdd(&bcur[d >> BSH], 1);
        bglu[pos] = (unsigned)s | ((unsigned)(d & (BSZ - 1)) << 16);
    } else if (i < 2 * EE) {
        int e = i - EE;
        int s = ld[e], d = ld[EE + e];
        int pos = atomicAdd(&bcur[NBK + (d >> BSH)], 1);
        bgld[pos] = (unsigned)s | ((unsigned)(d & (BSZ - 1)) << 16);
    } else {
        int e = i - 2 * EE;
        int r = pi[e], c = pi[EE + e];
        int pos = atomicAdd(&bcur[2 * NBK + (r >> BSH)], 1);
        bgpc[pos] = (unsigned)c | ((unsigned)(r & (BSZ - 1)) << 16);
        bgpv[pos] = pv[e];
    }
}

// per-(list,bucket) workgroup: stage bucket in LDS, local count+scan,
// in-place reorder to exact per-node CSR + write node offsets.
__global__ __launch_bounds__(256) void k_b2c(
    const int* __restrict__ bbase,
    unsigned* __restrict__ bglu, unsigned* __restrict__ bgld,
    unsigned* __restrict__ bgpc, float* __restrict__ bgpv,
    int* __restrict__ off)
{
    __shared__ int ecnt[BSZ];
    __shared__ int eoff[BSZ + 1];
    __shared__ unsigned buf[CAP];
    __shared__ float bufv[CAP];
    int bid  = blockIdx.x;
    int list = bid / NBK, b = bid - list * NBK;
    int base = bbase[list * (NBK + 1) + b];
    int end  = bbase[list * (NBK + 1) + b + 1];
    int size = end - base;
    int t = threadIdx.x;
    if (t < BSZ) ecnt[t] = 0;
    __syncthreads();
    unsigned* arr = (list == 0) ? bglu : (list == 1) ? bgld : bgpc;
    for (int i = t; i < size; i += 256) {
        unsigned v = arr[base + i];
        buf[i] = v;
        if (list == 2) bufv[i] = bgpv[base + i];
        atomicAdd(&ecnt[(v >> 16) & (BSZ - 1)], 1);
    }
    __syncthreads();
    if (t == 0) {
        int run = 0;
        for (int k = 0; k < BSZ; ++k) { eoff[k] = run; run += ecnt[k]; }
        eoff[BSZ] = run;
    }
    __syncthreads();
    int n0 = b << BSH;
    if (t < BSZ && n0 + t < NN) off[list * (NN + 1) + n0 + t] = base + eoff[t];
    if (t < BSZ) ecnt[t] = eoff[t];     // turn into cursors
    __syncthreads();
    for (int i = t; i < size; i += 256) {
        unsigned v = buf[i];
        int pos = atomicAdd(&ecnt[(v >> 16) & (BSZ - 1)], 1);
        arr[base + pos] = v;
        if (list == 2) bgpv[base + pos] = bufv[i];
    }
}

// ---------------------------------------------------------------------------
// one wave per node: in-register segment softmax + 4-way-ILP gather.
__global__ __launch_bounds__(256) void k_gather(
    const int* __restrict__ off,
    const unsigned* __restrict__ bglu, const unsigned* __restrict__ bgld,
    const unsigned* __restrict__ bgpc, const float* __restrict__ bgpv,
    const float* __restrict__ ssrc, const float* __restrict__ sdst,
    const float* __restrict__ h, const float* __restrict__ hp,
    float* __restrict__ out)
{
    int lane = threadIdx.x & 63;
    int wid  = blockIdx.x * (blockDim.x >> 6) + (threadIdx.x >> 6);
    int nw   = gridDim.x * (blockDim.x >> 6);
    for (int n = wid; n < NN; n += nw) {
        float a0 = 0.f, a1 = 0.f, a2 = 0.f, a3 = 0.f;
        float sd = sdst[n];
        for (int list = 0; list < 2; ++list) {
            const unsigned* ss = list ? bgld : bglu;
            const int* ob = off + list * (NN + 1);
            int b = ob[n], e = ob[n + 1];
            if (e <= b) continue;
            float m = -FLT_MAX, den = 0.f;
            for (int cb = b; cb < e; cb += 64) {
                int j = cb + lane;
                float ev = -FLT_MAX;
                if (j < e) ev = leaky(ssrc[ss[j] & 0xFFFFu] + sd);
                float cm = ev;
#pragma unroll
                for (int o = 32; o; o >>= 1) cm = fmaxf(cm, __shfl_xor(cm, o, 64));
                if (cm > m) { den *= __expf(m - cm); m = cm; }
                float ex = (j < e) ? __expf(ev - m) : 0.f;
#pragma unroll
                for (int o = 32; o; o >>= 1) ex += __shfl_xor(ex, o, 64);
                den += ex;
            }
            float inv = 1.f / (den + 1e-16f);
            for (int cb = b; cb < e; cb += 64) {
                int j = cb + lane;
                int sl = 0; float wl = 0.f;
                if (j < e) { sl = (int)(ss[j] & 0xFFFFu);
                             wl = __expf(leaky(ssrc[sl] + sd) - m) * inv; }
                int c64 = min(64, e - cb);
                int k = 0;
                for (; k + 4 <= c64; k += 4) {
                    int   s0 = __shfl(sl, k, 64),     s1 = __shfl(sl, k + 1, 64);
                    int   s2 = __shfl(sl, k + 2, 64), s3 = __shfl(sl, k + 3, 64);
                    float w0 = __shfl(wl, k, 64),     w1 = __shfl(wl, k + 1, 64);
                    float w2 = __shfl(wl, k + 2, 64), w3 = __shfl(wl, k + 3, 64);
                    a0 = fmaf(w0, h[s0 * 64 + lane], a0);
                    a1 = fmaf(w1, h[s1 * 64 + lane], a1);
                    a2 = fmaf(w2, h[s2 * 64 + lane], a2);
                    a3 = fmaf(w3, h[s3 * 64 + lane], a3);
                }
                for (; k < c64; ++k) {
                    int sj = __shfl(sl, k, 64); float wj = __shfl(wl, k, 64);
                    a0 = fmaf(wj, h[sj * 64 + lane], a0);
                }
            }
        }
        {   // p list
            const int* ob = off + 2 * (NN + 1);
            int b = ob[n], e = ob[n + 1];
            for (int cb = b; cb < e; cb += 64) {
                int j = cb + lane;
                int cl = 0; float vl = 0.f;
                if (j < e) { cl = (int)(bgpc[j] & 0xFFFFu); vl = bgpv[j]; }
                int c64 = min(64, e - cb);
                int k = 0;
                for (; k + 4 <= c64; k += 4) {
                    int   c0 = __shfl(cl, k, 64),     c1 = __shfl(cl, k + 1, 64);
                    int   c2 = __shfl(cl, k + 2, 64), c3 = __shfl(cl, k + 3, 64);
                    float v0 = __shfl(vl, k, 64),     v1 = __shfl(vl, k + 1, 64);
                    float v2 = __shfl(vl, k + 2, 64), v3 = __shfl(vl, k + 3, 64);
                    a0 = fmaf(v0, hp[c0 * 64 + lane], a0);
                    a1 = fmaf(v1, hp[c1 * 64 + lane], a1);
                    a2 = fmaf(v2, hp[c2 * 64 + lane], a2);
                    a3 = fmaf(v3, hp[c3 * 64 + lane], a3);
                }
                for (; k < c64; ++k) {
                    int cj = __shfl(cl, k, 64); float vj = __shfl(vl, k, 64);
                    a0 = fmaf(vj, hp[cj * 64 + lane], a0);
                }
            }
        }
        out[n * 64 + lane] = a0 + a1 + a2 + a3;
    }
}

// ---------------------------------------------------------------------------
extern "C" void kernel_launch(void* const* d_in, const int* in_sizes, int n_in,
                              void* d_out, int out_size, void* d_ws, size_t ws_size,
                              hipStream_t stream)
{
    const float* feat = (const float*)d_in[0];
    const float* Wg   = (const float*)d_in[1];
    const float* bg   = (const float*)d_in[2];
    const float* as_  = (const float*)d_in[3];
    const float* ad_  = (const float*)d_in[4];
    const float* Wp   = (const float*)d_in[5];
    const float* bp   = (const float*)d_in[6];
    const float* pv   = (const float*)d_in[7];
    const int*   lu   = (const int*)d_in[8];
    const int*   ld   = (const int*)d_in[9];
    const int*   pi   = (const int*)d_in[10];
    float* out = (float*)d_out;

    float* ws    = (float*)d_ws;
    float* h     = ws;                               // NN*64
    float* hp    = h + (size_t)NN * 64;              // NN*64
    float* ssrc  = hp + (size_t)NN * 64;             // NN
    float* sdst  = ssrc + NN;                        // NN
    int*   off   = (int*)(sdst + NN);                // 3*(NN+1)
    int*   bcnt  = off + 3 * (NN + 1);               // 3*NBK
    int*   bbase = bcnt + 3 * NBK;                   // 3*(NBK+1)
    int*   bcur  = bbase + 3 * (NBK + 1);            // 3*NBK
    unsigned* bglu = (unsigned*)(bcur + 3 * NBK);    // EE
    unsigned* bgld = bglu + EE;                      // EE
    unsigned* bgpc = bgld + EE;                      // EE
    float*    bgpv = (float*)(bgpc + EE);            // EE

    hipLaunchKernelGGL(k_gemm, dim3(2048), dim3(256), 0, stream,
                       feat, Wg, bg, as_, ad_, Wp, bp, h, hp, ssrc, sdst);
    hipLaunchKernelGGL(k_zero, dim3((3 * NBK + 255) / 256), dim3(256), 0, stream, bcnt);
    hipLaunchKernelGGL(k_bhist, dim3(1172), dim3(256), 0, stream, lu, ld, pi, bcnt);
    hipLaunchKernelGGL(k_bscan, dim3(1), dim3(256), 0, stream, bcnt, bbase, bcur, off);
    hipLaunchKernelGGL(k_bfill, dim3((3 * EE + 255) / 256), dim3(256), 0, stream,
                       lu, ld, pi, pv, bcur, bglu, bgld, bgpc, bgpv);
    hipLaunchKernelGGL(k_b2c, dim3(3 * NBK), dim3(256), 0, stream,
                       bbase, bglu, bgld, bgpc, bgpv, off);
    hipLaunchKernelGGL(k_gather, dim3(3125), dim3(256), 0, stream,
                       off, bglu, bgld, bgpc, bgpv, ssrc, sdst, h, hp, out);
}

// Round 4
// 378.691 us; speedup vs baseline: 3.5229x; 3.5229x over previous
//
#include <hip/hip_runtime.h>
#include <cfloat>

#define NN 50000
#define EE 1600000
#define NEG 0.2f
#define BSH 7
#define BSZ 128                       // nodes per bucket
#define NBK ((NN + BSZ - 1) / BSZ)    // 391
#define CAP 8192                      // k_b2c bucket staging capacity (avg ~4096)
#define TSZ 8192                      // k_bin tile size (edges)
#define NT  ((EE + TSZ - 1) / TSZ)    // 196 tiles per list

__device__ inline float leaky(float v) { return v >= 0.f ? v : NEG * v; }

// ---------------------------------------------------------------------------
// GEMM: h = feat@Wg + bg ; hp = feat@Wp + bp ; ssrc = h@a_src ; sdst = h@a_dst
__global__ __launch_bounds__(256) void k_gemm(
    const float* __restrict__ feat, const float* __restrict__ Wg,
    const float* __restrict__ bg, const float* __restrict__ as_,
    const float* __restrict__ ad_, const float* __restrict__ Wp,
    const float* __restrict__ bp,
    float* __restrict__ h, float* __restrict__ hp,
    float* __restrict__ ssrc, float* __restrict__ sdst)
{
    __shared__ float sWg[64 * 64];
    __shared__ float sWp[64 * 64];
    __shared__ float sb[4 * 64];
    int t = threadIdx.x;
    for (int i = t; i < 4096; i += 256) { sWg[i] = Wg[i]; sWp[i] = Wp[i]; }
    if (t < 64)       sb[t] = bg[t];
    else if (t < 128) sb[t] = bp[t - 64];
    else if (t < 192) sb[t] = as_[t - 128];
    else              sb[t] = ad_[t - 192];
    __syncthreads();

    int lane = t & 63;
    int w    = t >> 6;
    int nw   = (gridDim.x * blockDim.x) >> 6;
    for (int n = blockIdx.x * 4 + w; n < NN; n += nw) {
        float fv   = feat[n * 64 + lane];
        float accg = sb[lane];
        float accp = sb[64 + lane];
#pragma unroll
        for (int k = 0; k < 64; ++k) {
            float f = __shfl(fv, k, 64);
            accg = fmaf(f, sWg[k * 64 + lane], accg);
            accp = fmaf(f, sWp[k * 64 + lane], accp);
        }
        h [n * 64 + lane] = accg;
        hp[n * 64 + lane] = accp;
        float vs = accg * sb[128 + lane];
        float vd = accg * sb[192 + lane];
#pragma unroll
        for (int off = 32; off > 0; off >>= 1) {
            vs += __shfl_xor(vs, off, 64);
            vd += __shfl_xor(vd, off, 64);
        }
        if (lane == 0) { ssrc[n] = vs; sdst[n] = vd; }
    }
}

// ---------------------------------------------------------------------------
__global__ void k_zero(int* __restrict__ bcnt)
{
    int i = blockIdx.x * blockDim.x + threadIdx.x;
    if (i < 3 * NBK) bcnt[i] = 0;
}

// bucket histogram, LDS-privatized. Few blocks -> few flush atomics.
__global__ __launch_bounds__(256) void k_bhist(
    const int* __restrict__ lu, const int* __restrict__ ld,
    const int* __restrict__ pi, int* __restrict__ bcnt)
{
    __shared__ int lh[3 * NBK];
    for (int i = threadIdx.x; i < 3 * NBK; i += 256) lh[i] = 0;
    __syncthreads();
    int stride = gridDim.x * blockDim.x;
    for (int i = blockIdx.x * blockDim.x + threadIdx.x; i < 3 * EE; i += stride) {
        int slot;
        if (i < EE)          slot = 0 * NBK + (lu[EE + i] >> BSH);
        else if (i < 2 * EE) slot = 1 * NBK + (ld[i] >> BSH);
        else                 slot = 2 * NBK + (pi[i - 2 * EE] >> BSH);
        atomicAdd(&lh[slot], 1);
    }
    __syncthreads();
    for (int i = threadIdx.x; i < 3 * NBK; i += 256)
        if (lh[i]) atomicAdd(&bcnt[i], lh[i]);
}

// scan bucket counts per list -> region bases + padded cursors; off[l][NN]=EE.
__global__ __launch_bounds__(256) void k_bscan(
    const int* __restrict__ bcnt, int* __restrict__ bbase,
    int* __restrict__ bcur, int* __restrict__ off)
{
    __shared__ int part[256];
    int t = threadIdx.x;
    for (int l = 0; l < 3; ++l) {
        const int* cb = bcnt + l * NBK;
        int* bb = bbase + l * (NBK + 1);
        int* bc = bcur + l * NBK * 16;
        const int CH = (NBK + 255) / 256;
        int lo = t * CH, hi = min(lo + CH, NBK);
        int s = 0;
        for (int i = lo; i < hi; ++i) s += cb[i];
        part[t] = s;
        __syncthreads();
        for (int d = 1; d < 256; d <<= 1) {
            int v = 0;
            if (t >= d) v = part[t - d];
            __syncthreads();
            if (t >= d) part[t] += v;
            __syncthreads();
        }
        int run = (t == 0) ? 0 : part[t - 1];
        for (int i = lo; i < hi; ++i) { bb[i] = run; bc[i * 16] = run; run += cb[i]; }
        if (t == 0) { bb[NBK] = EE; off[l * (NN + 1) + NN] = EE; }
        __syncthreads();
    }
}

// tile-local bucket sort + chunk reservation, then coalesced write-out.
// payload: low16 = src (GAT) / col (p), high16 = full dst node id.
__global__ __launch_bounds__(256) void k_bin(
    const int* __restrict__ lu, const int* __restrict__ ld,
    const int* __restrict__ pi, const float* __restrict__ pv,
    int* __restrict__ bcur,
    unsigned* __restrict__ bglu, unsigned* __restrict__ bgld,
    unsigned* __restrict__ bgpc, float* __restrict__ bgpv)
{
    __shared__ int hist[NBK];       // counts, then cursors
    __shared__ int loff[NBK];       // tile-local exclusive scan
    __shared__ int gbase[NBK];      // reserved global base per bucket
    __shared__ int part[256];
    __shared__ unsigned stage[TSZ];
    __shared__ float stagev[TSZ];
    int t = threadIdx.x;
    for (int task = blockIdx.x; task < 3 * NT; task += gridDim.x) {
        int list = task / NT, tile = task - list * NT;
        int e0 = tile * TSZ, e1 = min(e0 + TSZ, EE), sz = e1 - e0;
        const int* srcp; const int* dstp;
        if (list == 0)      { srcp = lu;      dstp = lu + EE; }
        else if (list == 1) { srcp = ld;      dstp = ld + EE; }
        else                { srcp = pi + EE; dstp = pi; }
        for (int i = t; i < NBK; i += 256) hist[i] = 0;
        __syncthreads();
        // pass A: tile histogram in LDS
        for (int i = t; i < sz; i += 256)
            atomicAdd(&hist[dstp[e0 + i] >> BSH], 1);
        __syncthreads();
        // scan hist -> loff
        {
            const int CH = (NBK + 255) / 256;
            int lo = t * CH, hi = min(lo + CH, NBK);
            int s = 0;
            for (int i = lo; i < hi; ++i) s += hist[i];
            part[t] = s;
            __syncthreads();
            for (int d = 1; d < 256; d <<= 1) {
                int v = 0;
                if (t >= d) v = part[t - d];
                __syncthreads();
                if (t >= d) part[t] += v;
                __syncthreads();
            }
            int run = (t == 0) ? 0 : part[t - 1];
            for (int i = lo; i < hi; ++i) { loff[i] = run; run += hist[i]; }
        }
        __syncthreads();
        // reserve global ranges; convert hist -> local cursors
        for (int i = t; i < NBK; i += 256) {
            int c = hist[i];
            if (c) gbase[i] = atomicAdd(&bcur[(list * NBK + i) * 16], c);
            hist[i] = loff[i];
        }
        __syncthreads();
        // pass B: sort tile into LDS by bucket
        for (int i = t; i < sz; i += 256) {
            int d = dstp[e0 + i];
            int b = d >> BSH;
            unsigned pay = (unsigned)srcp[e0 + i] | ((unsigned)d << 16);
            int r = atomicAdd(&hist[b], 1);
            stage[r] = pay;
            if (list == 2) stagev[r] = pv[e0 + i];
        }
        __syncthreads();
        // write-out: contiguous runs per bucket
        unsigned* arr = (list == 0) ? bglu : (list == 1) ? bgld : bgpc;
        for (int i = t; i < sz; i += 256) {
            unsigned v = stage[i];
            int b = (int)(v >> (16 + BSH));
            int addr = gbase[b] + (i - loff[b]);
            arr[addr] = v;
            if (list == 2) bgpv[addr] = stagev[i];
        }
        __syncthreads();
    }
}

// per-(list,bucket) workgroup: stage bucket in LDS, count+scan nodes,
// in-place reorder to exact per-node CSR + write node offsets.
__global__ __launch_bounds__(256) void k_b2c(
    const int* __restrict__ bbase,
    unsigned* __restrict__ bglu, unsigned* __restrict__ bgld,
    unsigned* __restrict__ bgpc, float* __restrict__ bgpv,
    int* __restrict__ off)
{
    __shared__ int ecnt[BSZ];
    __shared__ int eoff[BSZ + 1];
    __shared__ unsigned buf[CAP];
    __shared__ float bufv[CAP];
    int bid  = blockIdx.x;
    int list = bid / NBK, b = bid - list * NBK;
    int base = bbase[list * (NBK + 1) + b];
    int end  = bbase[list * (NBK + 1) + b + 1];
    int size = end - base;
    int t = threadIdx.x;
    if (t < BSZ) ecnt[t] = 0;
    __syncthreads();
    unsigned* arr = (list == 0) ? bglu : (list == 1) ? bgld : bgpc;
    for (int i = t; i < size; i += 256) {
        unsigned v = arr[base + i];
        buf[i] = v;
        if (list == 2) bufv[i] = bgpv[base + i];
        atomicAdd(&ecnt[(v >> 16) & (BSZ - 1)], 1);
    }
    __syncthreads();
    if (t == 0) {
        int run = 0;
        for (int k = 0; k < BSZ; ++k) { eoff[k] = run; run += ecnt[k]; }
        eoff[BSZ] = run;
    }
    __syncthreads();
    int n0 = b << BSH;
    if (t < BSZ && n0 + t < NN) off[list * (NN + 1) + n0 + t] = base + eoff[t];
    if (t < BSZ) ecnt[t] = eoff[t];     // cursors
    __syncthreads();
    for (int i = t; i < size; i += 256) {
        unsigned v = buf[i];
        int pos = atomicAdd(&ecnt[(v >> 16) & (BSZ - 1)], 1);
        arr[base + pos] = v;
        if (list == 2) bgpv[base + pos] = bufv[i];
    }
}

// ---------------------------------------------------------------------------
// one wave per node: in-register segment softmax + 4-way-ILP gather.
__global__ __launch_bounds__(256) void k_gather(
    const int* __restrict__ off,
    const unsigned* __restrict__ bglu, const unsigned* __restrict__ bgld,
    const unsigned* __restrict__ bgpc, const float* __restrict__ bgpv,
    const float* __restrict__ ssrc, const float* __restrict__ sdst,
    const float* __restrict__ h, const float* __restrict__ hp,
    float* __restrict__ out)
{
    int lane = threadIdx.x & 63;
    int wid  = blockIdx.x * (blockDim.x >> 6) + (threadIdx.x >> 6);
    int nw   = gridDim.x * (blockDim.x >> 6);
    for (int n = wid; n < NN; n += nw) {
        float a0 = 0.f, a1 = 0.f, a2 = 0.f, a3 = 0.f;
        float sd = sdst[n];
        for (int list = 0; list < 2; ++list) {
            const unsigned* ss = list ? bgld : bglu;
            const int* ob = off + list * (NN + 1);
            int b = ob[n], e = ob[n + 1];
            if (e <= b) continue;
            float m = -FLT_MAX, den = 0.f;
            for (int cb = b; cb < e; cb += 64) {
                int j = cb + lane;
                float ev = -FLT_MAX;
                if (j < e) ev = leaky(ssrc[ss[j] & 0xFFFFu] + sd);
                float cm = ev;
#pragma unroll
                for (int o = 32; o; o >>= 1) cm = fmaxf(cm, __shfl_xor(cm, o, 64));
                if (cm > m) { den *= __expf(m - cm); m = cm; }
                float ex = (j < e) ? __expf(ev - m) : 0.f;
#pragma unroll
                for (int o = 32; o; o >>= 1) ex += __shfl_xor(ex, o, 64);
                den += ex;
            }
            float inv = 1.f / (den + 1e-16f);
            for (int cb = b; cb < e; cb += 64) {
                int j = cb + lane;
                int sl = 0; float wl = 0.f;
                if (j < e) { sl = (int)(ss[j] & 0xFFFFu);
                             wl = __expf(leaky(ssrc[sl] + sd) - m) * inv; }
                int c64 = min(64, e - cb);
                int k = 0;
                for (; k + 4 <= c64; k += 4) {
                    int   s0 = __shfl(sl, k, 64),     s1 = __shfl(sl, k + 1, 64);
                    int   s2 = __shfl(sl, k + 2, 64), s3 = __shfl(sl, k + 3, 64);
                    float w0 = __shfl(wl, k, 64),     w1 = __shfl(wl, k + 1, 64);
                    float w2 = __shfl(wl, k + 2, 64), w3 = __shfl(wl, k + 3, 64);
                    a0 = fmaf(w0, h[s0 * 64 + lane], a0);
                    a1 = fmaf(w1, h[s1 * 64 + lane], a1);
                    a2 = fmaf(w2, h[s2 * 64 + lane], a2);
                    a3 = fmaf(w3, h[s3 * 64 + lane], a3);
                }
                for (; k < c64; ++k) {
                    int sj = __shfl(sl, k, 64); float wj = __shfl(wl, k, 64);
                    a0 = fmaf(wj, h[sj * 64 + lane], a0);
                }
            }
        }
        {   // p list
            const int* ob = off + 2 * (NN + 1);
            int b = ob[n], e = ob[n + 1];
            for (int cb = b; cb < e; cb += 64) {
                int j = cb + lane;
                int cl = 0; float vl = 0.f;
                if (j < e) { cl = (int)(bgpc[j] & 0xFFFFu); vl = bgpv[j]; }
                int c64 = min(64, e - cb);
                int k = 0;
                for (; k + 4 <= c64; k += 4) {
                    int   c0 = __shfl(cl, k, 64),     c1 = __shfl(cl, k + 1, 64);
                    int   c2 = __shfl(cl, k + 2, 64), c3 = __shfl(cl, k + 3, 64);
                    float v0 = __shfl(vl, k, 64),     v1 = __shfl(vl, k + 1, 64);
                    float v2 = __shfl(vl, k + 2, 64), v3 = __shfl(vl, k + 3, 64);
                    a0 = fmaf(v0, hp[c0 * 64 + lane], a0);
                    a1 = fmaf(v1, hp[c1 * 64 + lane], a1);
                    a2 = fmaf(v2, hp[c2 * 64 + lane], a2);
                    a3 = fmaf(v3, hp[c3 * 64 + lane], a3);
                }
                for (; k < c64; ++k) {
                    int cj = __shfl(cl, k, 64); float vj = __shfl(vl, k, 64);
                    a0 = fmaf(vj, hp[cj * 64 + lane], a0);
                }
            }
        }
        out[n * 64 + lane] = a0 + a1 + a2 + a3;
    }
}

// ---------------------------------------------------------------------------
extern "C" void kernel_launch(void* const* d_in, const int* in_sizes, int n_in,
                              void* d_out, int out_size, void* d_ws, size_t ws_size,
                              hipStream_t stream)
{
    const float* feat = (const float*)d_in[0];
    const float* Wg   = (const float*)d_in[1];
    const float* bg   = (const float*)d_in[2];
    const float* as_  = (const float*)d_in[3];
    const float* ad_  = (const float*)d_in[4];
    const float* Wp   = (const float*)d_in[5];
    const float* bp   = (const float*)d_in[6];
    const float* pv   = (const float*)d_in[7];
    const int*   lu   = (const int*)d_in[8];
    const int*   ld   = (const int*)d_in[9];
    const int*   pi   = (const int*)d_in[10];
    float* out = (float*)d_out;

    float* ws    = (float*)d_ws;
    float* h     = ws;                               // NN*64
    float* hp    = h + (size_t)NN * 64;              // NN*64
    float* ssrc  = hp + (size_t)NN * 64;             // NN
    float* sdst  = ssrc + NN;                        // NN
    int*   off   = (int*)(sdst + NN);                // 3*(NN+1)
    int*   bcnt  = off + 3 * (NN + 1);               // 3*NBK
    int*   bbase = bcnt + 3 * NBK;                   // 3*(NBK+1)
    int*   bcur  = bbase + 3 * (NBK + 1);            // 3*NBK*16 (64B-padded)
    unsigned* bglu = (unsigned*)(bcur + 3 * NBK * 16); // EE
    unsigned* bgld = bglu + EE;                      // EE
    unsigned* bgpc = bgld + EE;                      // EE
    float*    bgpv = (float*)(bgpc + EE);            // EE

    hipLaunchKernelGGL(k_gemm, dim3(2048), dim3(256), 0, stream,
                       feat, Wg, bg, as_, ad_, Wp, bp, h, hp, ssrc, sdst);
    hipLaunchKernelGGL(k_zero, dim3((3 * NBK + 255) / 256), dim3(256), 0, stream, bcnt);
    hipLaunchKernelGGL(k_bhist, dim3(320), dim3(256), 0, stream, lu, ld, pi, bcnt);
    hipLaunchKernelGGL(k_bscan, dim3(1), dim3(256), 0, stream, bcnt, bbase, bcur, off);
    hipLaunchKernelGGL(k_bin, dim3(3 * NT), dim3(256), 0, stream,
                       lu, ld, pi, pv, bcur, bglu, bgld, bgpc, bgpv);
    hipLaunchKernelGGL(k_b2c, dim3(3 * NBK), dim3(256), 0, stream,
                       bbase, bglu, bgld, bgpc, bgpv, off);
    hipLaunchKernelGGL(k_gather, dim3(3125), dim3(256), 0, stream,
                       off, bglu, bgld, bgpc, bgpv, ssrc, sdst, h, hp, out);
}

// Round 5
// 350.690 us; speedup vs baseline: 3.8042x; 1.0798x over previous
//
#include <hip/hip_runtime.h>
#include <cfloat>

#define NN 50000
#define EE 1600000
#define NEG 0.2f
#define BSH 7
#define BSZ 128                       // nodes per bucket
#define NBK ((NN + BSZ - 1) / BSZ)    // 391
#define CAP 8192                      // k_b2c bucket staging capacity (avg ~4096)
#define TSZ 8192                      // k_bin tile size (edges)
#define NT  ((EE + TSZ - 1) / TSZ)    // 196 tiles per list

__device__ inline float leaky(float v) { return v >= 0.f ? v : NEG * v; }

__device__ inline unsigned short f2bf(float f) {
    unsigned u = __float_as_uint(f);
    u += 0x7FFFu + ((u >> 16) & 1u);          // round-to-nearest-even
    return (unsigned short)(u >> 16);
}
__device__ inline float bf2f(unsigned short s) {
    return __uint_as_float(((unsigned)s) << 16);
}

// ---------------------------------------------------------------------------
// GEMM: h16 = bf16(feat@Wg+bg) ; hp16 = bf16(feat@Wp+bp) ; ssrc/sdst f32.
__global__ __launch_bounds__(256) void k_gemm(
    const float* __restrict__ feat, const float* __restrict__ Wg,
    const float* __restrict__ bg, const float* __restrict__ as_,
    const float* __restrict__ ad_, const float* __restrict__ Wp,
    const float* __restrict__ bp,
    unsigned short* __restrict__ h16, unsigned short* __restrict__ hp16,
    float* __restrict__ ssrc, float* __restrict__ sdst)
{
    __shared__ float sWg[64 * 64];
    __shared__ float sWp[64 * 64];
    __shared__ float sb[4 * 64];
    int t = threadIdx.x;
    for (int i = t; i < 4096; i += 256) { sWg[i] = Wg[i]; sWp[i] = Wp[i]; }
    if (t < 64)       sb[t] = bg[t];
    else if (t < 128) sb[t] = bp[t - 64];
    else if (t < 192) sb[t] = as_[t - 128];
    else              sb[t] = ad_[t - 192];
    __syncthreads();

    int lane = t & 63;
    int w    = t >> 6;
    int nw   = (gridDim.x * blockDim.x) >> 6;
    for (int n = blockIdx.x * 4 + w; n < NN; n += nw) {
        float fv   = feat[n * 64 + lane];
        float accg = sb[lane];
        float accp = sb[64 + lane];
#pragma unroll
        for (int k = 0; k < 64; ++k) {
            float f = __shfl(fv, k, 64);
            accg = fmaf(f, sWg[k * 64 + lane], accg);
            accp = fmaf(f, sWp[k * 64 + lane], accp);
        }
        h16 [n * 64 + lane] = f2bf(accg);
        hp16[n * 64 + lane] = f2bf(accp);
        float vs = accg * sb[128 + lane];
        float vd = accg * sb[192 + lane];
#pragma unroll
        for (int off = 32; off > 0; off >>= 1) {
            vs += __shfl_xor(vs, off, 64);
            vd += __shfl_xor(vd, off, 64);
        }
        if (lane == 0) { ssrc[n] = vs; sdst[n] = vd; }
    }
}

// ---------------------------------------------------------------------------
__global__ void k_zero(int* __restrict__ bcnt)
{
    int i = blockIdx.x * blockDim.x + threadIdx.x;
    if (i < 3 * NBK) bcnt[i] = 0;
}

// bucket histogram, LDS-privatized.
__global__ __launch_bounds__(256) void k_bhist(
    const int* __restrict__ lu, const int* __restrict__ ld,
    const int* __restrict__ pi, int* __restrict__ bcnt)
{
    __shared__ int lh[3 * NBK];
    for (int i = threadIdx.x; i < 3 * NBK; i += 256) lh[i] = 0;
    __syncthreads();
    int stride = gridDim.x * blockDim.x;
    for (int i = blockIdx.x * blockDim.x + threadIdx.x; i < 3 * EE; i += stride) {
        int slot;
        if (i < EE)          slot = 0 * NBK + (lu[EE + i] >> BSH);
        else if (i < 2 * EE) slot = 1 * NBK + (ld[i] >> BSH);
        else                 slot = 2 * NBK + (pi[i - 2 * EE] >> BSH);
        atomicAdd(&lh[slot], 1);
    }
    __syncthreads();
    for (int i = threadIdx.x; i < 3 * NBK; i += 256)
        if (lh[i]) atomicAdd(&bcnt[i], lh[i]);
}

// scan bucket counts per list -> region bases + padded cursors; off[l][NN]=EE.
__global__ __launch_bounds__(256) void k_bscan(
    const int* __restrict__ bcnt, int* __restrict__ bbase,
    int* __restrict__ bcur, int* __restrict__ off)
{
    __shared__ int part[256];
    int t = threadIdx.x;
    for (int l = 0; l < 3; ++l) {
        const int* cb = bcnt + l * NBK;
        int* bb = bbase + l * (NBK + 1);
        int* bc = bcur + l * NBK * 16;
        const int CH = (NBK + 255) / 256;
        int lo = t * CH, hi = min(lo + CH, NBK);
        int s = 0;
        for (int i = lo; i < hi; ++i) s += cb[i];
        part[t] = s;
        __syncthreads();
        for (int d = 1; d < 256; d <<= 1) {
            int v = 0;
            if (t >= d) v = part[t - d];
            __syncthreads();
            if (t >= d) part[t] += v;
            __syncthreads();
        }
        int run = (t == 0) ? 0 : part[t - 1];
        for (int i = lo; i < hi; ++i) { bb[i] = run; bc[i * 16] = run; run += cb[i]; }
        if (t == 0) { bb[NBK] = EE; off[l * (NN + 1) + NN] = EE; }
        __syncthreads();
    }
}

// tile-local bucket sort + chunk reservation, then coalesced write-out.
// payload: low16 = src (GAT) / col (p), high16 = full dst node id.
__global__ __launch_bounds__(256) void k_bin(
    const int* __restrict__ lu, const int* __restrict__ ld,
    const int* __restrict__ pi, const float* __restrict__ pv,
    int* __restrict__ bcur,
    unsigned* __restrict__ bglu, unsigned* __restrict__ bgld,
    unsigned* __restrict__ bgpc, float* __restrict__ bgpv)
{
    __shared__ int hist[NBK];
    __shared__ int loff[NBK];
    __shared__ int gbase[NBK];
    __shared__ int part[256];
    __shared__ unsigned stage[TSZ];
    __shared__ float stagev[TSZ];
    int t = threadIdx.x;
    for (int task = blockIdx.x; task < 3 * NT; task += gridDim.x) {
        int list = task / NT, tile = task - list * NT;
        int e0 = tile * TSZ, e1 = min(e0 + TSZ, EE), sz = e1 - e0;
        const int* srcp; const int* dstp;
        if (list == 0)      { srcp = lu;      dstp = lu + EE; }
        else if (list == 1) { srcp = ld;      dstp = ld + EE; }
        else                { srcp = pi + EE; dstp = pi; }
        for (int i = t; i < NBK; i += 256) hist[i] = 0;
        __syncthreads();
        for (int i = t; i < sz; i += 256)
            atomicAdd(&hist[dstp[e0 + i] >> BSH], 1);
        __syncthreads();
        {
            const int CH = (NBK + 255) / 256;
            int lo = t * CH, hi = min(lo + CH, NBK);
            int s = 0;
            for (int i = lo; i < hi; ++i) s += hist[i];
            part[t] = s;
            __syncthreads();
            for (int d = 1; d < 256; d <<= 1) {
                int v = 0;
                if (t >= d) v = part[t - d];
                __syncthreads();
                if (t >= d) part[t] += v;
                __syncthreads();
            }
            int run = (t == 0) ? 0 : part[t - 1];
            for (int i = lo; i < hi; ++i) { loff[i] = run; run += hist[i]; }
        }
        __syncthreads();
        for (int i = t; i < NBK; i += 256) {
            int c = hist[i];
            if (c) gbase[i] = atomicAdd(&bcur[(list * NBK + i) * 16], c);
            hist[i] = loff[i];
        }
        __syncthreads();
        for (int i = t; i < sz; i += 256) {
            int d = dstp[e0 + i];
            int b = d >> BSH;
            unsigned pay = (unsigned)srcp[e0 + i] | ((unsigned)d << 16);
            int r = atomicAdd(&hist[b], 1);
            stage[r] = pay;
            if (list == 2) stagev[r] = pv[e0 + i];
        }
        __syncthreads();
        unsigned* arr = (list == 0) ? bglu : (list == 1) ? bgld : bgpc;
        for (int i = t; i < sz; i += 256) {
            unsigned v = stage[i];
            int b = (int)(v >> (16 + BSH));
            int addr = gbase[b] + (i - loff[b]);
            arr[addr] = v;
            if (list == 2) bgpv[addr] = stagev[i];
        }
        __syncthreads();
    }
}

// per-(list,bucket) workgroup: stage bucket in LDS, count+scan nodes,
// in-place reorder to exact per-node CSR + write node offsets.
__global__ __launch_bounds__(256) void k_b2c(
    const int* __restrict__ bbase,
    unsigned* __restrict__ bglu, unsigned* __restrict__ bgld,
    unsigned* __restrict__ bgpc, float* __restrict__ bgpv,
    int* __restrict__ off)
{
    __shared__ int ecnt[BSZ];
    __shared__ int eoff[BSZ + 1];
    __shared__ unsigned buf[CAP];
    __shared__ float bufv[CAP];
    int bid  = blockIdx.x;
    int list = bid / NBK, b = bid - list * NBK;
    int base = bbase[list * (NBK + 1) + b];
    int end  = bbase[list * (NBK + 1) + b + 1];
    int size = end - base;
    int t = threadIdx.x;
    if (t < BSZ) ecnt[t] = 0;
    __syncthreads();
    unsigned* arr = (list == 0) ? bglu : (list == 1) ? bgld : bgpc;
    for (int i = t; i < size; i += 256) {
        unsigned v = arr[base + i];
        buf[i] = v;
        if (list == 2) bufv[i] = bgpv[base + i];
        atomicAdd(&ecnt[(v >> 16) & (BSZ - 1)], 1);
    }
    __syncthreads();
    if (t == 0) {
        int run = 0;
        for (int k = 0; k < BSZ; ++k) { eoff[k] = run; run += ecnt[k]; }
        eoff[BSZ] = run;
    }
    __syncthreads();
    int n0 = b << BSH;
    if (t < BSZ && n0 + t < NN) off[list * (NN + 1) + n0 + t] = base + eoff[t];
    if (t < BSZ) ecnt[t] = eoff[t];
    __syncthreads();
    for (int i = t; i < size; i += 256) {
        unsigned v = buf[i];
        int pos = atomicAdd(&ecnt[(v >> 16) & (BSZ - 1)], 1);
        arr[base + pos] = v;
        if (list == 2) bgpv[base + pos] = bufv[i];
    }
}

// ---------------------------------------------------------------------------
// one wave per node: in-register segment softmax + 4-way-ILP bf16 gather.
__global__ __launch_bounds__(256) void k_gather(
    const int* __restrict__ off,
    const unsigned* __restrict__ bglu, const unsigned* __restrict__ bgld,
    const unsigned* __restrict__ bgpc, const float* __restrict__ bgpv,
    const float* __restrict__ ssrc, const float* __restrict__ sdst,
    const unsigned short* __restrict__ h16, const unsigned short* __restrict__ hp16,
    float* __restrict__ out)
{
    int lane = threadIdx.x & 63;
    int wid  = blockIdx.x * (blockDim.x >> 6) + (threadIdx.x >> 6);
    int nw   = gridDim.x * (blockDim.x >> 6);
    for (int n = wid; n < NN; n += nw) {
        float a0 = 0.f, a1 = 0.f, a2 = 0.f, a3 = 0.f;
        float sd = sdst[n];
        for (int list = 0; list < 2; ++list) {
            const unsigned* ss = list ? bgld : bglu;
            const int* ob = off + list * (NN + 1);
            int b = ob[n], e = ob[n + 1];
            int deg = e - b;
            if (deg <= 0) continue;
            if (deg <= 64) {
                // fast path: whole segment in one wave chunk, ev kept in reg.
                int sl = 0; float ev = -FLT_MAX;
                if (lane < deg) { sl = (int)(ss[b + lane] & 0xFFFFu);
                                  ev = leaky(ssrc[sl] + sd); }
                float m = ev;
#pragma unroll
                for (int o = 32; o; o >>= 1) m = fmaxf(m, __shfl_xor(m, o, 64));
                float ex = (lane < deg) ? __expf(ev - m) : 0.f;
                float den = ex;
#pragma unroll
                for (int o = 32; o; o >>= 1) den += __shfl_xor(den, o, 64);
                float wl = ex * (1.f / (den + 1e-16f));
                int k = 0;
                for (; k + 4 <= deg; k += 4) {
                    int   s0 = __shfl(sl, k, 64),     s1 = __shfl(sl, k + 1, 64);
                    int   s2 = __shfl(sl, k + 2, 64), s3 = __shfl(sl, k + 3, 64);
                    float w0 = __shfl(wl, k, 64),     w1 = __shfl(wl, k + 1, 64);
                    float w2 = __shfl(wl, k + 2, 64), w3 = __shfl(wl, k + 3, 64);
                    a0 = fmaf(w0, bf2f(h16[s0 * 64 + lane]), a0);
                    a1 = fmaf(w1, bf2f(h16[s1 * 64 + lane]), a1);
                    a2 = fmaf(w2, bf2f(h16[s2 * 64 + lane]), a2);
                    a3 = fmaf(w3, bf2f(h16[s3 * 64 + lane]), a3);
                }
                for (; k < deg; ++k) {
                    int sj = __shfl(sl, k, 64); float wj = __shfl(wl, k, 64);
                    a0 = fmaf(wj, bf2f(h16[sj * 64 + lane]), a0);
                }
                continue;
            }
            // general path
            float m = -FLT_MAX, den = 0.f;
            for (int cb = b; cb < e; cb += 64) {
                int j = cb + lane;
                float ev = -FLT_MAX;
                if (j < e) ev = leaky(ssrc[ss[j] & 0xFFFFu] + sd);
                float cm = ev;
#pragma unroll
                for (int o = 32; o; o >>= 1) cm = fmaxf(cm, __shfl_xor(cm, o, 64));
                if (cm > m) { den *= __expf(m - cm); m = cm; }
                float ex = (j < e) ? __expf(ev - m) : 0.f;
#pragma unroll
                for (int o = 32; o; o >>= 1) ex += __shfl_xor(ex, o, 64);
                den += ex;
            }
            float inv = 1.f / (den + 1e-16f);
            for (int cb = b; cb < e; cb += 64) {
                int j = cb + lane;
                int sl = 0; float wl = 0.f;
                if (j < e) { sl = (int)(ss[j] & 0xFFFFu);
                             wl = __expf(leaky(ssrc[sl] + sd) - m) * inv; }
                int c64 = min(64, e - cb);
                int k = 0;
                for (; k + 4 <= c64; k += 4) {
                    int   s0 = __shfl(sl, k, 64),     s1 = __shfl(sl, k + 1, 64);
                    int   s2 = __shfl(sl, k + 2, 64), s3 = __shfl(sl, k + 3, 64);
                    float w0 = __shfl(wl, k, 64),     w1 = __shfl(wl, k + 1, 64);
                    float w2 = __shfl(wl, k + 2, 64), w3 = __shfl(wl, k + 3, 64);
                    a0 = fmaf(w0, bf2f(h16[s0 * 64 + lane]), a0);
                    a1 = fmaf(w1, bf2f(h16[s1 * 64 + lane]), a1);
                    a2 = fmaf(w2, bf2f(h16[s2 * 64 + lane]), a2);
                    a3 = fmaf(w3, bf2f(h16[s3 * 64 + lane]), a3);
                }
                for (; k < c64; ++k) {
                    int sj = __shfl(sl, k, 64); float wj = __shfl(wl, k, 64);
                    a0 = fmaf(wj, bf2f(h16[sj * 64 + lane]), a0);
                }
            }
        }
        {   // p list
            const int* ob = off + 2 * (NN + 1);
            int b = ob[n], e = ob[n + 1];
            for (int cb = b; cb < e; cb += 64) {
                int j = cb + lane;
                int cl = 0; float vl = 0.f;
                if (j < e) { cl = (int)(bgpc[j] & 0xFFFFu); vl = bgpv[j]; }
                int c64 = min(64, e - cb);
                int k = 0;
                for (; k + 4 <= c64; k += 4) {
                    int   c0 = __shfl(cl, k, 64),     c1 = __shfl(cl, k + 1, 64);
                    int   c2 = __shfl(cl, k + 2, 64), c3 = __shfl(cl, k + 3, 64);
                    float v0 = __shfl(vl, k, 64),     v1 = __shfl(vl, k + 1, 64);
                    float v2 = __shfl(vl, k + 2, 64), v3 = __shfl(vl, k + 3, 64);
                    a0 = fmaf(v0, bf2f(hp16[c0 * 64 + lane]), a0);
                    a1 = fmaf(v1, bf2f(hp16[c1 * 64 + lane]), a1);
                    a2 = fmaf(v2, bf2f(hp16[c2 * 64 + lane]), a2);
                    a3 = fmaf(v3, bf2f(hp16[c3 * 64 + lane]), a3);
                }
                for (; k < c64; ++k) {
                    int cj = __shfl(cl, k, 64); float vj = __shfl(vl, k, 64);
                    a0 = fmaf(vj, bf2f(hp16[cj * 64 + lane]), a0);
                }
            }
        }
        out[n * 64 + lane] = a0 + a1 + a2 + a3;
    }
}

// ---------------------------------------------------------------------------
extern "C" void kernel_launch(void* const* d_in, const int* in_sizes, int n_in,
                              void* d_out, int out_size, void* d_ws, size_t ws_size,
                              hipStream_t stream)
{
    const float* feat = (const float*)d_in[0];
    const float* Wg   = (const float*)d_in[1];
    const float* bg   = (const float*)d_in[2];
    const float* as_  = (const float*)d_in[3];
    const float* ad_  = (const float*)d_in[4];
    const float* Wp   = (const float*)d_in[5];
    const float* bp   = (const float*)d_in[6];
    const float* pv   = (const float*)d_in[7];
    const int*   lu   = (const int*)d_in[8];
    const int*   ld   = (const int*)d_in[9];
    const int*   pi   = (const int*)d_in[10];
    float* out = (float*)d_out;

    unsigned short* h16  = (unsigned short*)d_ws;        // NN*64 (2B)
    unsigned short* hp16 = h16 + (size_t)NN * 64;        // NN*64 (2B)
    float* fbase = (float*)(hp16 + (size_t)NN * 64);
    float* ssrc  = fbase;                                // NN
    float* sdst  = ssrc + NN;                            // NN
    int*   off   = (int*)(sdst + NN);                    // 3*(NN+1)
    int*   bcnt  = off + 3 * (NN + 1);                   // 3*NBK
    int*   bbase = bcnt + 3 * NBK;                       // 3*(NBK+1)
    int*   bcur  = bbase + 3 * (NBK + 1);                // 3*NBK*16 (64B-padded)
    unsigned* bglu = (unsigned*)(bcur + 3 * NBK * 16);   // EE
    unsigned* bgld = bglu + EE;                          // EE
    unsigned* bgpc = bgld + EE;                          // EE
    float*    bgpv = (float*)(bgpc + EE);                // EE

    hipLaunchKernelGGL(k_gemm, dim3(2048), dim3(256), 0, stream,
                       feat, Wg, bg, as_, ad_, Wp, bp, h16, hp16, ssrc, sdst);
    hipLaunchKernelGGL(k_zero, dim3((3 * NBK + 255) / 256), dim3(256), 0, stream, bcnt);
    hipLaunchKernelGGL(k_bhist, dim3(320), dim3(256), 0, stream, lu, ld, pi, bcnt);
    hipLaunchKernelGGL(k_bscan, dim3(1), dim3(256), 0, stream, bcnt, bbase, bcur, off);
    hipLaunchKernelGGL(k_bin, dim3(3 * NT), dim3(256), 0, stream,
                       lu, ld, pi, pv, bcur, bglu, bgld, bgpc, bgpv);
    hipLaunchKernelGGL(k_b2c, dim3(3 * NBK), dim3(256), 0, stream,
                       bbase, bglu, bgld, bgpc, bgpv, off);
    hipLaunchKernelGGL(k_gather, dim3(3125), dim3(256), 0, stream,
                       off, bglu, bgld, bgpc, bgpv, ssrc, sdst, h16, hp16, out);
}